// Round 4
// baseline (120.857 us; speedup 1.0000x reference)
//
#include <hip/hip_runtime.h>
#include <stdint.h>

#define NB 8
#define NS 256
#define ND 1024
#define EPSF 1e-5f
#define BIGF 3.0e38f

typedef __attribute__((ext_vector_type(8))) short short8;
typedef __attribute__((ext_vector_type(4))) float f32x4;

__device__ __forceinline__ unsigned short f2bf(float f) {
  unsigned int u = __float_as_uint(f);
  u = (u + 0x7FFFu + ((u >> 16) & 1u)) >> 16;
  return (unsigned short)u;
}
__device__ __forceinline__ float bf2f(unsigned short u) {
  return __uint_as_float((unsigned int)u << 16);
}

// ---- fp32 -> bf16 convert, fused exact diag ||x_t||^2 and inv_xnorm ----
// one wave per row (b,s): 2048 rows
__global__ __launch_bounds__(256) void k_convert(const float* __restrict__ x,
                                                 unsigned short* __restrict__ xb,
                                                 float* __restrict__ DGa,
                                                 float* __restrict__ IXa) {
  int row = blockIdx.x * 4 + (threadIdx.x >> 6);
  int lane = threadIdx.x & 63;
  size_t base = (size_t)row * ND;
  float sq = 0.f;
#pragma unroll
  for (int c = 0; c < 4; ++c) {
    size_t o = base + c * 256 + lane * 4;
    float4 v = *reinterpret_cast<const float4*>(x + o);
    ushort4 ob;
    ob.x = f2bf(v.x); ob.y = f2bf(v.y); ob.z = f2bf(v.z); ob.w = f2bf(v.w);
    *reinterpret_cast<ushort4*>(xb + o) = ob;
    sq += v.x * v.x + v.y * v.y + v.z * v.z + v.w * v.w;
  }
#pragma unroll
  for (int off = 32; off; off >>= 1) sq += __shfl_xor(sq, off);
  if (lane == 0) {
    DGa[row] = sq;
    IXa[row] = 1.0f / sqrtf(sq);   // inf if 0 -> forces slow path everywhere
  }
}

// ---- Y[rr,d] = sum_{s<=rr} x[s,d]  (inclusive prefix along s) ----
// ONE WAVE PER COLUMN (b,d): lane handles rows 4*lane..4*lane+3, wave shfl-scan
__global__ __launch_bounds__(256) void k_ypfx(const unsigned short* __restrict__ xb,
                                              unsigned short* __restrict__ yb) {
  int wid = (blockIdx.x * 256 + threadIdx.x) >> 6;   // 0..8191
  int lane = threadIdx.x & 63;
  int b = wid >> 10;
  int d = wid & 1023;
  const unsigned short* xr = xb + ((size_t)b << 18) + d;
  unsigned short* yr = yb + ((size_t)b << 18) + d;
  int s0 = lane << 2;
  float v0 = bf2f(xr[(size_t)(s0 + 0) * ND]);
  float v1 = bf2f(xr[(size_t)(s0 + 1) * ND]);
  float v2 = bf2f(xr[(size_t)(s0 + 2) * ND]);
  float v3 = bf2f(xr[(size_t)(s0 + 3) * ND]);
  float sum = v0 + v1 + v2 + v3;
  float sc = sum;
#pragma unroll
  for (int off = 1; off < 64; off <<= 1) {
    float n = __shfl_up(sc, off);
    if (lane >= off) sc += n;
  }
  float y0 = (sc - sum) + v0;
  float y1 = y0 + v1;
  float y2 = y1 + v2;
  float y3 = y2 + v3;
  yr[(size_t)(s0 + 0) * ND] = f2bf(y0);
  yr[(size_t)(s0 + 1) * ND] = f2bf(y1);
  yr[(size_t)(s0 + 2) * ND] = f2bf(y2);
  yr[(size_t)(s0 + 3) * ND] = f2bf(y3);
}

// ---- C[r,t] = Y_r . x_t  (bf16 MFMA, K-split 2, partials Cp0/Cp1) ----
// wave job: 32x32 tile of (rr,t), rr = r-1
__global__ __launch_bounds__(256) void k_gemmC(const unsigned short* __restrict__ yb,
                                               const unsigned short* __restrict__ xb,
                                               float* __restrict__ cp) {
  int gw = ((blockIdx.x << 8) + threadIdx.x) >> 6;  // 0..1023
  int lane = threadIdx.x & 63;
  int b  = gw & 7;
  int mt = (gw >> 3) & 7;
  int nt = (gw >> 6) & 7;
  int ks = (gw >> 9) & 1;
  const unsigned short* Ab = yb + ((size_t)b << 18) + ((size_t)(mt << 5) << 10);
  const unsigned short* Bb = xb + ((size_t)b << 18) + ((size_t)(nt << 5) << 10);
  int lr = lane & 15;
  int lk = (lane >> 4) << 3;
  f32x4 acc00 = {0.f,0.f,0.f,0.f}, acc01 = {0.f,0.f,0.f,0.f};
  f32x4 acc10 = {0.f,0.f,0.f,0.f}, acc11 = {0.f,0.f,0.f,0.f};
  int kbase = (ks << 9) + lk;
#pragma unroll 2
  for (int kk = 0; kk < 512; kk += 32) {
    int ko = kbase + kk;
    short8 a0  = *reinterpret_cast<const short8*>(Ab + ((size_t)lr << 10) + ko);
    short8 a1  = *reinterpret_cast<const short8*>(Ab + ((size_t)(16 + lr) << 10) + ko);
    short8 bb0 = *reinterpret_cast<const short8*>(Bb + ((size_t)lr << 10) + ko);
    short8 bb1 = *reinterpret_cast<const short8*>(Bb + ((size_t)(16 + lr) << 10) + ko);
    acc00 = __builtin_amdgcn_mfma_f32_16x16x32_bf16(a0, bb0, acc00, 0, 0, 0);
    acc01 = __builtin_amdgcn_mfma_f32_16x16x32_bf16(a0, bb1, acc01, 0, 0, 0);
    acc10 = __builtin_amdgcn_mfma_f32_16x16x32_bf16(a1, bb0, acc10, 0, 0, 0);
    acc11 = __builtin_amdgcn_mfma_f32_16x16x32_bf16(a1, bb1, acc11, 0, 0, 0);
  }
  // C/D layout: col = lane&15, row = (lane>>4)*4 + j   [measured m89]
  float* G = cp + (size_t)ks * (NB * NS * NS) + ((size_t)b << 16);
  int r0 = (mt << 5) + ((lane >> 4) << 2);
  int c0 = (nt << 5) + lr;
#pragma unroll
  for (int j = 0; j < 4; ++j) {
    G[(r0 + j) * NS + c0]           = acc00[j];
    G[(r0 + j) * NS + c0 + 16]      = acc01[j];
    G[(r0 + 16 + j) * NS + c0]      = acc10[j];
    G[(r0 + 16 + j) * NS + c0 + 16] = acc11[j];
  }
}

// ---- reduce partials -> C (257 rows, row 0 = 0), S2[r,c] = prefix of C row ----
// one wave per (b,r): 2056 waves
__global__ __launch_bounds__(256) void k_scan(const float* __restrict__ cp,
                                              float* __restrict__ C, float* __restrict__ S2) {
  int id = blockIdx.x * 4 + (threadIdx.x >> 6);   // 0..2055
  int lane = threadIdx.x & 63;
  int b = id / 257;
  int r = id - b * 257;
  float* Crow = C + ((size_t)b * 257 + r) * NS;
  float* Srow = S2 + ((size_t)b * 257 + r) * 257;
  const float* p0 = cp + (((size_t)b << 8) + (r - 1)) * NS;
  const float* p1 = p0 + (size_t)NB * NS * NS;
  if (lane == 0) Srow[0] = 0.f;
  float run = 0.f;
  for (int c0 = 0; c0 < NS; c0 += 64) {
    float v = 0.f;
    if (r > 0) v = p0[c0 + lane] + p1[c0 + lane];
    Crow[c0 + lane] = v;
#pragma unroll
    for (int off = 1; off < 64; off <<= 1) {
      float n = __shfl_up(v, off);
      if (lane >= off) v += n;
    }
    Srow[c0 + lane + 1] = run + v;
    run += __shfl(v, 63);
  }
}

// ---- tropical GEMM: worst[i,j] = min_t (W[j+1,t]-W[i,t]) / sn(i,j) ----
// grid covers ALL 32x64 tiles (8b x 8it x 4jt); invalid tiles/cells write 0
__global__ __launch_bounds__(256) void k_trop(const float* __restrict__ C,
                                              const float* __restrict__ S2,
                                              const float* __restrict__ IXa,
                                              const float* __restrict__ DGa,
                                              float* __restrict__ out) {
  __shared__ float As[64][36];   // As[tt][ii]
  __shared__ float Bs[64][68];   // Bs[tt][jj]
  __shared__ float wred[4];
  int blk = blockIdx.x;
  int b = blk >> 5;
  int tix = blk & 31;
  int i0 = (tix >> 2) << 5;
  int j0 = (tix & 3) << 6;
  int tid = threadIdx.x;
  float* outb = out + ((size_t)b << 16);

  if (i0 >= j0 + 63) {           // fully-invalid tile: zero-fill
    float4 z = {0.f, 0.f, 0.f, 0.f};
    float* p = outb + (size_t)(i0 + (tid >> 3)) * NS + j0 + ((tid & 7) << 3);
    reinterpret_cast<float4*>(p)[0] = z;
    reinterpret_cast<float4*>(p)[1] = z;
    return;
  }

  const float* Cb = C + (size_t)b * 257 * NS;
  const float* IXb = IXa + b * NS;

  // per-batch wmax (block reduce)
  float wv0 = IXb[tid];
#pragma unroll
  for (int off = 32; off; off >>= 1) wv0 = fmaxf(wv0, __shfl_xor(wv0, off));
  if ((tid & 63) == 0) wred[tid >> 6] = wv0;
  __syncthreads();
  float wmb = fmaxf(fmaxf(wred[0], wred[1]), fmaxf(wred[2], wred[3]));

  int ii0 = (tid >> 4) << 1;     // 0,2,...,30
  int jj0 = (tid & 15) << 2;     // 0,4,...,60
  float acc[8];
#pragma unroll
  for (int k = 0; k < 8; ++k) acc[k] = BIGF;

  int rA = tid >> 4;             // 0..15
  int c4 = (tid & 15) << 2;      // 0..60

  for (int t0 = i0 & ~63; t0 < j0 + 64; t0 += 64) {
    __syncthreads();
    float4 wv = *reinterpret_cast<const float4*>(IXb + t0 + c4);
#pragma unroll
    for (int p = 0; p < 2; ++p) {      // A: rows i0..i0+31
      int r = i0 + p * 16 + rA;
      float4 v = *reinterpret_cast<const float4*>(Cb + (size_t)r * NS + t0 + c4);
      As[c4 + 0][p * 16 + rA] = v.x * wv.x;
      As[c4 + 1][p * 16 + rA] = v.y * wv.y;
      As[c4 + 2][p * 16 + rA] = v.z * wv.z;
      As[c4 + 3][p * 16 + rA] = v.w * wv.w;
    }
#pragma unroll
    for (int p = 0; p < 4; ++p) {      // B: rows j0+1..j0+64
      int r = j0 + 1 + p * 16 + rA;
      float4 v = *reinterpret_cast<const float4*>(Cb + (size_t)r * NS + t0 + c4);
      Bs[c4 + 0][p * 16 + rA] = v.x * wv.x;
      Bs[c4 + 1][p * 16 + rA] = v.y * wv.y;
      Bs[c4 + 2][p * 16 + rA] = v.z * wv.z;
      Bs[c4 + 3][p * 16 + rA] = v.w * wv.w;
    }
    __syncthreads();

    int thA = i0 + ii0 - t0;   // a[k] valid iff tt >= thA + k
    int thB = j0 + jj0 - t0;   // b[l] valid iff tt <= thB + l
    if (thA <= -1 && thB >= 63) {
#pragma unroll 4
      for (int tt = 0; tt < 64; ++tt) {
        float2 a = *reinterpret_cast<const float2*>(&As[tt][ii0]);
        float4 bv = *reinterpret_cast<const float4*>(&Bs[tt][jj0]);
        acc[0] = fminf(acc[0], bv.x - a.x);
        acc[1] = fminf(acc[1], bv.y - a.x);
        acc[2] = fminf(acc[2], bv.z - a.x);
        acc[3] = fminf(acc[3], bv.w - a.x);
        acc[4] = fminf(acc[4], bv.x - a.y);
        acc[5] = fminf(acc[5], bv.y - a.y);
        acc[6] = fminf(acc[6], bv.z - a.y);
        acc[7] = fminf(acc[7], bv.w - a.y);
      }
    } else {
#pragma unroll 4
      for (int tt = 0; tt < 64; ++tt) {
        float2 a = *reinterpret_cast<const float2*>(&As[tt][ii0]);
        float4 bv = *reinterpret_cast<const float4*>(&Bs[tt][jj0]);
        float a0 = (tt >= thA)     ? a.x  : -BIGF;
        float a1 = (tt >= thA + 1) ? a.y  : -BIGF;
        float b0 = (tt <= thB)     ? bv.x :  BIGF;
        float b1 = (tt <= thB + 1) ? bv.y :  BIGF;
        float b2 = (tt <= thB + 2) ? bv.z :  BIGF;
        float b3 = (tt <= thB + 3) ? bv.w :  BIGF;
        acc[0] = fminf(acc[0], b0 - a0);
        acc[1] = fminf(acc[1], b1 - a0);
        acc[2] = fminf(acc[2], b2 - a0);
        acc[3] = fminf(acc[3], b3 - a0);
        acc[4] = fminf(acc[4], b0 - a1);
        acc[5] = fminf(acc[5], b1 - a1);
        acc[6] = fminf(acc[6], b2 - a1);
        acc[7] = fminf(acc[7], b3 - a1);
      }
    }
  }

  // epilogue: res = min_num / sn, 0 for invalid cells; vector stores cover tile
  const float* S2b = S2 + (size_t)b * 257 * 257;
  const float* DGb = DGa + b * NS;
#pragma unroll
  for (int k = 0; k < 2; ++k) {
    int i = i0 + ii0 + k;
    float o4[4];
    float s2ii = S2b[(size_t)i * 257 + i];
#pragma unroll
    for (int l = 0; l < 4; ++l) {
      int j = j0 + jj0 + l;
      float res = 0.f;
      if (i >= 1 && j > i) {
        float s2jj = S2b[(size_t)(j + 1) * 257 + (j + 1)];
        float s2ij = S2b[(size_t)i * 257 + (j + 1)];
        float s2ji = S2b[(size_t)(j + 1) * 257 + i];
        float ssq = (s2jj - s2ij) - (s2ji - s2ii);
        float sn = sqrtf(fmaxf(ssq, 0.f));
        float win = (float)(j - i + 1);
        if (sn >= EPSF * win * wmb) {
          res = acc[k * 4 + l] / sn;               // fast path: EPS never binds
        } else {
          float mn = sn / win;
          float m = BIGF;
          const float* r2 = Cb + (size_t)(j + 1) * NS;
          const float* r1 = Cb + (size_t)i * NS;
          for (int t = i; t <= j; ++t) {
            float num = r2[t] - r1[t];
            float xn = sqrtf(fmaxf(DGb[t], 0.f));
            float den = fmaxf(mn * xn, EPSF);
            m = fminf(m, num / win / den);
          }
          res = m;
        }
      }
      o4[l] = res;
    }
    float4 st = {o4[0], o4[1], o4[2], o4[3]};
    *reinterpret_cast<float4*>(outb + (size_t)i * NS + j0 + jj0) = st;
  }
}

extern "C" void kernel_launch(void* const* d_in, const int* in_sizes, int n_in,
                              void* d_out, int out_size, void* d_ws, size_t ws_size,
                              hipStream_t stream) {
  (void)in_sizes; (void)n_in; (void)ws_size; (void)out_size;
  const float* x = (const float*)d_in[0];
  float* out = (float*)d_out;
  char* ws = (char*)d_ws;
  unsigned short* Xb = (unsigned short*)(ws);                 //  4,194,304 B
  unsigned short* Yb = (unsigned short*)(ws + 4194304);       //  4,194,304 B
  float* Cp  = (float*)(ws + 8388608);                        //  4,194,304 B (2 x 8 x 256 x 256)
  float* C   = (float*)(ws + 12582912);                       //  2,105,344 B (8 x 257 x 256)
  float* S2  = (float*)(ws + 14688256);                       //  2,113,568 B (8 x 257 x 257)
  float* DGa = (float*)(ws + 16801824);                       //  8,192 B
  float* IXa = (float*)(ws + 16810016);                       //  8,192 B

  k_convert<<<512, 256, 0, stream>>>(x, Xb, DGa, IXa);
  k_ypfx<<<2048, 256, 0, stream>>>(Xb, Yb);
  k_gemmC<<<256, 256, 0, stream>>>(Yb, Xb, Cp);
  k_scan<<<514, 256, 0, stream>>>(Cp, C, S2);
  k_trop<<<256, 256, 0, stream>>>(C, S2, IXa, DGa, out);
}